// Round 6
// baseline (5605.700 us; speedup 1.0000x reference)
//
#include <hip/hip_runtime.h>
#include <stdint.h>

#define NB 64
#define NS 512
#define NI 512
#define NH 512

typedef __attribute__((ext_vector_type(8))) short bf16x8;
typedef __attribute__((ext_vector_type(4))) float f32x4;
typedef __attribute__((ext_vector_type(4))) unsigned u32x4;

__device__ __forceinline__ unsigned short f2bf(float f) {
  unsigned u = __float_as_uint(f);
  return (unsigned short)((u + 0x7fffu + ((u >> 16) & 1u)) >> 16);
}
__device__ __forceinline__ float bf2f(unsigned short h) {
  return __uint_as_float(((unsigned)h) << 16);
}
__device__ __forceinline__ float sigm(float x) { return 1.0f / (1.0f + __expf(-x)); }
__device__ __forceinline__ float tanh_f(float x) {
  float e = __expf(-2.0f * fabsf(x));
  return copysignf((1.0f - e) / (1.0f + e), x);
}

// s-permutation: within each 64-entry j-block, reorder so a consumer lane's
// 16 entries (k = q*8+e and q*8+e+32) are CONTIGUOUS 128B:
// j = c*32 + q*8 + e  ->  s = q*16 + c*8 + e   (within block)
__device__ __forceinline__ int sperm(int j) {
  int local = j & 63;
  return (j & ~63) | (((local >> 3) & 3) << 4) | ((local >> 5) << 3) | (local & 7);
}

// ws layout (u32 units):
//  [1024, 1024+131072):  hexV[2][64 b][512 s] u64 {lo = packed h (bf16 hi|lo), hi = version}
//  [132096, +8388608):   x_bf16 as u16[64][512][512]
#define HEXV_OFF 1024
#define XBF_OFF 132096
#define WS_BYTES_NEEDED ((size_t)XBF_OFF * 4 + (size_t)NB * NS * NI * 2)

__global__ __launch_bounds__(256) void k_xconv(const float* __restrict__ x,
                                               unsigned short* __restrict__ xb) {
  size_t i = ((size_t)blockIdx.x * 256 + threadIdx.x) * 4;
  float4 v = *(const float4*)(x + i);
  ushort4 o;
  o.x = f2bf(v.x); o.y = f2bf(v.y); o.z = f2bf(v.z); o.w = f2bf(v.w);
  *(ushort4*)(xb + i) = o;
}

__global__ __launch_bounds__(256) void k_init(const float* __restrict__ h0,
                                              unsigned long long* __restrict__ hexv) {
  int idx = blockIdx.x * 256 + threadIdx.x;  // 32768 entries
  int b = idx >> 9, j = idx & 511;
  float v = h0[idx];
  unsigned short hi = f2bf(v);
  unsigned short lo = f2bf(v - bf2f(hi));
  unsigned pk = (unsigned)hi | ((unsigned)lo << 16);
  int s = sperm(j);
  hexv[(size_t)b * 512 + s] = (unsigned long long)pk | (1ull << 32);  // buf0: h ver 1 (used at t=0)
  hexv[32768 + (size_t)b * 512 + s] = 0ull;                           // buf1: cleared (replay-safe)
}

// Persistent cooperative LSTM kernel.
// grid 256 WGs x 512 thr. WG: m=bid&3 (16 batches), n=bid>>2 (8 h-cols -> 32 gate rows).
// wave w = K-eighth (64 K-cols); computes BOTH 16-gate-row tiles (u=0,1).
// h exchange: SINGLE round trip. Producer fire-and-forget sc1 u64 store of
// {packed h, version}. Consumer retry-loads its contiguous 128B fragment with
// coalesced cache-bypass (sc1) dwordx4 loads until all 16 versions == t+1.
// No flags, no acks, no fences; backpressure via the transitive version chain.
__global__ __launch_bounds__(512, 2) void k_lstm(
    const float* __restrict__ Wih, const float* __restrict__ bih,
    const float* __restrict__ Whh, const float* __restrict__ bhh,
    const float* __restrict__ c0, float* __restrict__ out,
    unsigned int* __restrict__ ws) {
  const int tid = threadIdx.x;
  const int lane = tid & 63;
  const int w = tid >> 6;   // K-eighth
  const int k0 = w * 64;
  const int m = blockIdx.x & 3;
  const int n = blockIdx.x >> 2;

  unsigned long long* hexv = (unsigned long long*)(ws + HEXV_OFF);
  const unsigned short* xb = (const unsigned short*)(ws + XBF_OFF);

  // B-fragment lane mapping: col=lane&15, k=(lane>>4)*8+r
  const int c = lane & 15;
  const int q = lane >> 4;
  const int jj = c & 3;
  const int gate = c >> 2;

  // ---- weight fragments (hi/lo bf16 split), 2 tiles x 2 K-chunks ----
  bf16x8 whh_hi[2][2], whh_lo[2][2], wih_hi[2][2], wih_lo[2][2];
  float biasr[2];
#pragma unroll
  for (int u = 0; u < 2; ++u) {
    const int wrow = gate * NH + n * 8 + u * 4 + jj;
#pragma unroll
    for (int kc = 0; kc < 2; ++kc) {
      const int kb = k0 + kc * 32 + q * 8;
      const float* ph = Whh + (size_t)wrow * NH + kb;
      const float* pi = Wih + (size_t)wrow * NI + kb;
      float4 a0 = *(const float4*)ph, a1 = *(const float4*)(ph + 4);
      float4 b0 = *(const float4*)pi, b1 = *(const float4*)(pi + 4);
      float vh[8] = {a0.x, a0.y, a0.z, a0.w, a1.x, a1.y, a1.z, a1.w};
      float vi[8] = {b0.x, b0.y, b0.z, b0.w, b1.x, b1.y, b1.z, b1.w};
#pragma unroll
      for (int r = 0; r < 8; ++r) {
        unsigned short h16 = f2bf(vh[r]);
        whh_hi[u][kc][r] = (short)h16;
        whh_lo[u][kc][r] = (short)f2bf(vh[r] - bf2f(h16));
        unsigned short i16 = f2bf(vi[r]);
        wih_hi[u][kc][r] = (short)i16;
        wih_lo[u][kc][r] = (short)f2bf(vi[r] - bf2f(i16));
      }
    }
    biasr[u] = bih[wrow] + bhh[wrow];
  }

  // epilogue state (reducer waves 0,1): lane = (b=lane&15, j2=lane>>4)
  const int eb = m * 16 + (lane & 15);
  const int j2 = lane >> 4;
  const int jg = n * 8 + (w & 1) * 4 + j2;  // valid for reducer waves
  const int spg = sperm(jg);
  float cst = c0[(size_t)eb * NH + jg];

  __shared__ float part[2][8][4][64];  // [tile][wave][reg][lane], lane-stride-1
  __shared__ float gl[2][16][17];

  const unsigned short* xbase = xb + (size_t)eb * NS * NI + k0 + q * 8;

  // preload x fragments for t=0
  bf16x8 xfa0 = *(const bf16x8*)(xbase);
  bf16x8 xfa1 = *(const bf16x8*)(xbase + 32);

  // this wave's h fragment base: contiguous 128B (16 u64 entries)
  const char* hfrag = (const char*)(hexv + (size_t)eb * 512) + (w * 512 + q * 128);

  for (int t = 0; t < NS; ++t) {
    // x-path MFMA (loads long in flight; independent of h)
    f32x4 acc0 = {0.f, 0.f, 0.f, 0.f};
    f32x4 acc1 = {0.f, 0.f, 0.f, 0.f};
    acc0 = __builtin_amdgcn_mfma_f32_16x16x32_bf16(xfa0, wih_hi[0][0], acc0, 0, 0, 0);
    acc0 = __builtin_amdgcn_mfma_f32_16x16x32_bf16(xfa0, wih_lo[0][0], acc0, 0, 0, 0);
    acc1 = __builtin_amdgcn_mfma_f32_16x16x32_bf16(xfa0, wih_hi[1][0], acc1, 0, 0, 0);
    acc1 = __builtin_amdgcn_mfma_f32_16x16x32_bf16(xfa0, wih_lo[1][0], acc1, 0, 0, 0);
    acc0 = __builtin_amdgcn_mfma_f32_16x16x32_bf16(xfa1, wih_hi[0][1], acc0, 0, 0, 0);
    acc0 = __builtin_amdgcn_mfma_f32_16x16x32_bf16(xfa1, wih_lo[0][1], acc0, 0, 0, 0);
    acc1 = __builtin_amdgcn_mfma_f32_16x16x32_bf16(xfa1, wih_hi[1][1], acc1, 0, 0, 0);
    acc1 = __builtin_amdgcn_mfma_f32_16x16x32_bf16(xfa1, wih_lo[1][1], acc1, 0, 0, 0);

    // retry-load h fragment (coalesced sc1 dwordx4, one vmcnt wait) until fresh
    const char* hb = hfrag + (size_t)(t & 1) * (32768 * 8);
    const unsigned tgt = (unsigned)(t + 1);
    u32x4 v0, v1, v2, v3, v4, v5, v6, v7;
    int ok;
    do {
      asm volatile(
          "global_load_dwordx4 %0, %8, off sc1\n\t"
          "global_load_dwordx4 %1, %8, off offset:16 sc1\n\t"
          "global_load_dwordx4 %2, %8, off offset:32 sc1\n\t"
          "global_load_dwordx4 %3, %8, off offset:48 sc1\n\t"
          "global_load_dwordx4 %4, %8, off offset:64 sc1\n\t"
          "global_load_dwordx4 %5, %8, off offset:80 sc1\n\t"
          "global_load_dwordx4 %6, %8, off offset:96 sc1\n\t"
          "global_load_dwordx4 %7, %8, off offset:112 sc1\n\t"
          "s_waitcnt vmcnt(0)"
          : "=&v"(v0), "=&v"(v1), "=&v"(v2), "=&v"(v3),
            "=&v"(v4), "=&v"(v5), "=&v"(v6), "=&v"(v7)
          : "v"(hb)
          : "memory");
      ok = (v0[1] == tgt) & (v0[3] == tgt) & (v1[1] == tgt) & (v1[3] == tgt) &
           (v2[1] == tgt) & (v2[3] == tgt) & (v3[1] == tgt) & (v3[3] == tgt) &
           (v4[1] == tgt) & (v4[3] == tgt) & (v5[1] == tgt) & (v5[3] == tgt) &
           (v6[1] == tgt) & (v6[3] == tgt) & (v7[1] == tgt) & (v7[3] == tgt);
    } while (!__all(ok));

    // h-path MFMA, K-chunk 0 (data words: even u32 of each u64)
    {
      unsigned pw[8] = {v0[0], v0[2], v1[0], v1[2], v2[0], v2[2], v3[0], v3[2]};
      bf16x8 hh, hl;
#pragma unroll
      for (int r = 0; r < 8; ++r) {
        hh[r] = (short)(pw[r] & 0xffffu);
        hl[r] = (short)(pw[r] >> 16);
      }
      acc0 = __builtin_amdgcn_mfma_f32_16x16x32_bf16(hh, whh_hi[0][0], acc0, 0, 0, 0);
      acc0 = __builtin_amdgcn_mfma_f32_16x16x32_bf16(hl, whh_hi[0][0], acc0, 0, 0, 0);
      acc0 = __builtin_amdgcn_mfma_f32_16x16x32_bf16(hh, whh_lo[0][0], acc0, 0, 0, 0);
      acc1 = __builtin_amdgcn_mfma_f32_16x16x32_bf16(hh, whh_hi[1][0], acc1, 0, 0, 0);
      acc1 = __builtin_amdgcn_mfma_f32_16x16x32_bf16(hl, whh_hi[1][0], acc1, 0, 0, 0);
      acc1 = __builtin_amdgcn_mfma_f32_16x16x32_bf16(hh, whh_lo[1][0], acc1, 0, 0, 0);
    }
    // h-path MFMA, K-chunk 1
    {
      unsigned pw[8] = {v4[0], v4[2], v5[0], v5[2], v6[0], v6[2], v7[0], v7[2]};
      bf16x8 hh, hl;
#pragma unroll
      for (int r = 0; r < 8; ++r) {
        hh[r] = (short)(pw[r] & 0xffffu);
        hl[r] = (short)(pw[r] >> 16);
      }
      acc0 = __builtin_amdgcn_mfma_f32_16x16x32_bf16(hh, whh_hi[0][1], acc0, 0, 0, 0);
      acc0 = __builtin_amdgcn_mfma_f32_16x16x32_bf16(hl, whh_hi[0][1], acc0, 0, 0, 0);
      acc0 = __builtin_amdgcn_mfma_f32_16x16x32_bf16(hh, whh_lo[0][1], acc0, 0, 0, 0);
      acc1 = __builtin_amdgcn_mfma_f32_16x16x32_bf16(hh, whh_hi[1][1], acc1, 0, 0, 0);
      acc1 = __builtin_amdgcn_mfma_f32_16x16x32_bf16(hl, whh_hi[1][1], acc1, 0, 0, 0);
      acc1 = __builtin_amdgcn_mfma_f32_16x16x32_bf16(hh, whh_lo[1][1], acc1, 0, 0, 0);
    }

#pragma unroll
    for (int r = 0; r < 4; ++r) {
      part[0][w][r][lane] = acc0[r];
      part[1][w][r][lane] = acc1[r];
    }
    __syncthreads();  // S2: part visible (cheap drain: h-loads already waited)

    const int tn = (t + 1 < NS) ? t + 1 : t;
    bf16x8 xfn0, xfn1;
    if (w < 2) {  // reducer wave w handles tile u=w
      float g[4];
#pragma unroll
      for (int r = 0; r < 4; ++r) {
        float s = biasr[w];
#pragma unroll
        for (int ww = 0; ww < 8; ++ww) s += part[w][ww][r][lane];
        g[r] = s;
        gl[w][q * 4 + r][c] = g[r];  // D layout: row(batch)=(lane>>4)*4+r, col=lane&15
      }
      // same-wave LDS RAW: compiler inserts lgkmcnt waits
      const int bb = lane & 15;
      float gi = gl[w][bb][j2];
      float gf = gl[w][bb][4 + j2];
      float gg = gl[w][bb][8 + j2];
      float go = gl[w][bb][12 + j2];
      float cn = sigm(gf) * cst + sigm(gi) * tanh_f(gg);
      cst = cn;
      float hv = sigm(go) * tanh_f(cn);

      // publish: ONE fire-and-forget sc1 u64 store {packed h, version t+2}
      unsigned short ha = f2bf(hv), la = f2bf(hv - bf2f(ha));
      unsigned long long val =
          (unsigned long long)((unsigned)ha | ((unsigned)la << 16)) |
          ((unsigned long long)(unsigned)(t + 2) << 32);
      __hip_atomic_store(hexv + (size_t)((t + 1) & 1) * 32768 + (size_t)eb * 512 + spg,
                         val, __ATOMIC_RELAXED, __HIP_MEMORY_SCOPE_AGENT);

      // deferred, non-critical stores (normal cached path; drained at next S2)
      out[((size_t)eb * NS + t) * NH + jg] = hv;
      if (t == NS - 1) {
        size_t hoff = (size_t)NB * NS * NH;
        out[hoff + (size_t)eb * NH + jg] = hv;
        out[hoff + (size_t)NB * NH + (size_t)eb * NH + jg] = cn;
      }
      const unsigned short* xrn = xbase + (size_t)tn * NI;
      xfn0 = *(const bf16x8*)(xrn);
      xfn1 = *(const bf16x8*)(xrn + 32);
    } else {
      // writer waves: prefetch next x during reducer epilogue
      const unsigned short* xrn = xbase + (size_t)tn * NI;
      xfn0 = *(const bf16x8*)(xrn);
      xfn1 = *(const bf16x8*)(xrn + 32);
    }

    // S1: raw barrier (lgkm only — do NOT drain vmcnt; out-stores/x-prefetch fly on)
    asm volatile("s_waitcnt lgkmcnt(0)" ::: "memory");
    __builtin_amdgcn_s_barrier();

    xfa0 = xfn0;
    xfa1 = xfn1;
  }
}

extern "C" void kernel_launch(void* const* d_in, const int* in_sizes, int n_in,
                              void* d_out, int out_size, void* d_ws, size_t ws_size,
                              hipStream_t stream) {
  if (ws_size < WS_BYTES_NEEDED) return;  // fail visibly (poisoned d_out) rather than corrupt

  const float* x   = (const float*)d_in[0];
  const float* h0  = (const float*)d_in[1];
  const float* c0  = (const float*)d_in[2];
  const float* Wih = (const float*)d_in[3];
  const float* bih = (const float*)d_in[4];
  const float* Whh = (const float*)d_in[5];
  const float* bhh = (const float*)d_in[6];
  float* out = (float*)d_out;
  unsigned int* ws = (unsigned int*)d_ws;
  unsigned short* xbptr = (unsigned short*)(ws + XBF_OFF);
  unsigned long long* hexv = (unsigned long long*)(ws + HEXV_OFF);

  k_xconv<<<dim3(16384), dim3(256), 0, stream>>>(x, xbptr);
  k_init<<<dim3(128), dim3(256), 0, stream>>>(h0, hexv);

  void* args[] = {(void*)&Wih, (void*)&bih, (void*)&Whh, (void*)&bhh,
                  (void*)&c0,  (void*)&out, (void*)&ws};
  hipLaunchCooperativeKernel((const void*)k_lstm, dim3(256), dim3(512), args, 0, stream);
}

// Round 7
// 3300.597 us; speedup vs baseline: 1.6984x; 1.6984x over previous
//
#include <hip/hip_runtime.h>
#include <stdint.h>

#define NB 64
#define NS 512
#define NI 512
#define NH 512

typedef __attribute__((ext_vector_type(8))) short bf16x8;
typedef __attribute__((ext_vector_type(4))) float f32x4;

__device__ __forceinline__ unsigned short f2bf(float f) {
  unsigned u = __float_as_uint(f);
  return (unsigned short)((u + 0x7fffu + ((u >> 16) & 1u)) >> 16);
}
__device__ __forceinline__ float bf2f(unsigned short h) {
  return __uint_as_float(((unsigned)h) << 16);
}
__device__ __forceinline__ float sigm(float x) { return 1.0f / (1.0f + __expf(-x)); }
__device__ __forceinline__ float tanh_f(float x) {
  float e = __expf(-2.0f * fabsf(x));
  return copysignf((1.0f - e) / (1.0f + e), x);
}

// ws layout (u32 units):
//  [0,512):              flags[4 m-groups][128], idx = n*2 + tile; monotonic step counters
//  [1024, 1024+65536):   h_ex[2 bufs][64 b][512 j]  (packed bf16 hi | lo<<16)
//  [66560, +8388608):    x_bf16 as u16[64][512][512]
#define FLAGS_OFF 0
#define HEX_OFF 1024
#define XBF_OFF 66560
#define WS_BYTES_NEEDED (XBF_OFF * 4 + (size_t)NB * NS * NI * 2)

__global__ __launch_bounds__(256) void k_xconv(const float* __restrict__ x,
                                               unsigned short* __restrict__ xb) {
  size_t i = ((size_t)blockIdx.x * 256 + threadIdx.x) * 4;
  float4 v = *(const float4*)(x + i);
  ushort4 o;
  o.x = f2bf(v.x); o.y = f2bf(v.y); o.z = f2bf(v.z); o.w = f2bf(v.w);
  *(ushort4*)(xb + i) = o;
}

__global__ __launch_bounds__(256) void k_init(const float* __restrict__ h0,
                                              unsigned int* __restrict__ ws) {
  int idx = blockIdx.x * 256 + threadIdx.x;
  if (idx < NB * NH) {
    float v = h0[idx];
    unsigned short hi = f2bf(v);
    unsigned short lo = f2bf(v - bf2f(hi));
    ws[HEX_OFF + idx] = (unsigned)hi | ((unsigned)lo << 16);
  }
  if (idx < 512) ws[FLAGS_OFF + idx] = 1u;  // h version 0 available
}

// Persistent cooperative LSTM kernel.
// grid 256 WGs x 512 thr. WG: m=bid&3 (16 batches), n=bid>>2 (8 h-cols -> 32 gate rows).
// wave w = K-eighth (64 K-cols); computes BOTH 16-gate-row tiles (u=0,1).
// h exchange (no fences, L1/L2 never invalidated):
//   producers: sc1 store to MALL + vmcnt ack + sc1 flag (proven R2-R5 path)
//   consumers: loader waves 6,7 each poll their 64 half-flags, then stage their
//   16KB half via global_load_lds with aux=17 (SC0|SC1 -> cache-bypassing,
//   MALL-coherent, fully coalesced, fire-and-forget; ONE round trip).
// Reducer waves 0,1 split the epilogue (tile 0/1). Raw barriers: only the
// loaders drain vmcnt at S1; S2 drains lgkm only.
__global__ __launch_bounds__(512, 2) void k_lstm(
    const float* __restrict__ Wih, const float* __restrict__ bih,
    const float* __restrict__ Whh, const float* __restrict__ bhh,
    const float* __restrict__ c0, float* __restrict__ out,
    unsigned int* __restrict__ ws) {
  const int tid = threadIdx.x;
  const int lane = tid & 63;
  const int w = tid >> 6;   // K-eighth
  const int k0 = w * 64;
  const int m = blockIdx.x & 3;
  const int n = blockIdx.x >> 2;

  unsigned int* flags = ws + FLAGS_OFF + m * 128;
  unsigned int* hex = ws + HEX_OFF;
  const unsigned short* xb = (const unsigned short*)(ws + XBF_OFF);

  // B-fragment lane mapping: col=lane&15, k=(lane>>4)*8+r
  const int c = lane & 15;
  const int q = lane >> 4;
  const int jj = c & 3;
  const int gate = c >> 2;

  // ---- weight fragments (hi/lo bf16 split), 2 tiles x 2 K-chunks ----
  bf16x8 whh_hi[2][2], whh_lo[2][2], wih_hi[2][2], wih_lo[2][2];
  float biasr[2];
#pragma unroll
  for (int u = 0; u < 2; ++u) {
    const int wrow = gate * NH + n * 8 + u * 4 + jj;
#pragma unroll
    for (int kc = 0; kc < 2; ++kc) {
      const int kb = k0 + kc * 32 + q * 8;
      const float* ph = Whh + (size_t)wrow * NH + kb;
      const float* pi = Wih + (size_t)wrow * NI + kb;
      float4 a0 = *(const float4*)ph, a1 = *(const float4*)(ph + 4);
      float4 b0 = *(const float4*)pi, b1 = *(const float4*)(pi + 4);
      float vh[8] = {a0.x, a0.y, a0.z, a0.w, a1.x, a1.y, a1.z, a1.w};
      float vi[8] = {b0.x, b0.y, b0.z, b0.w, b1.x, b1.y, b1.z, b1.w};
#pragma unroll
      for (int r = 0; r < 8; ++r) {
        unsigned short h16 = f2bf(vh[r]);
        whh_hi[u][kc][r] = (short)h16;
        whh_lo[u][kc][r] = (short)f2bf(vh[r] - bf2f(h16));
        unsigned short i16 = f2bf(vi[r]);
        wih_hi[u][kc][r] = (short)i16;
        wih_lo[u][kc][r] = (short)f2bf(vi[r] - bf2f(i16));
      }
    }
    biasr[u] = bih[wrow] + bhh[wrow];
  }

  // epilogue state (reducer waves 0,1): lane = (b=lane&15, j2=lane>>4)
  const int eb = m * 16 + (lane & 15);
  const int j2 = lane >> 4;
  const int jg = n * 8 + (w & 1) * 4 + j2;  // meaningful for reducer waves
  float cst = c0[(size_t)eb * NH + jg];

  // LDS: staged h block (row stride 516 u32 -> row-pad kills multi-row aliasing;
  // each 1KB DMA window stays contiguous), partials, gates
  __shared__ unsigned Lhex[16][516];
  __shared__ float part[2][8][4][64];  // [tile][wave][reg][lane], lane-stride-1
  __shared__ float gl[2][16][17];

  const unsigned short* xbase = xb + (size_t)eb * NS * NI + k0 + q * 8;

  // preload x fragments for t=0
  bf16x8 xfa0 = *(const bf16x8*)(xbase);
  bf16x8 xfa1 = *(const bf16x8*)(xbase + 32);

  for (int t = 0; t < NS; ++t) {
    f32x4 acc0 = {0.f, 0.f, 0.f, 0.f};
    f32x4 acc1 = {0.f, 0.f, 0.f, 0.f};

    if (w >= 6) {
      // loader wave lh: poll the 64 flags of the WGs producing cols [lh*256, +256)
      const int lh = w - 6;
      const unsigned tgt = (unsigned)(t + 1);
      const unsigned* fp = flags + lh * 64 + lane;
      unsigned fl = __hip_atomic_load(fp, __ATOMIC_RELAXED, __HIP_MEMORY_SCOPE_AGENT);
      while (!__all((int)(fl >= tgt)))
        fl = __hip_atomic_load(fp, __ATOMIC_RELAXED, __HIP_MEMORY_SCOPE_AGENT);
      asm volatile("" ::: "memory");  // keep DMA below the poll

      // stage 16 rows x 1KB half-rows, cache-bypassing (aux=17: sc0|sc1 -> MALL)
      const unsigned* src = hex + (size_t)(t & 1) * (NB * NH) + (size_t)m * 16 * NH + lh * 256;
#pragma unroll
      for (int bl = 0; bl < 16; ++bl) {
        __builtin_amdgcn_global_load_lds(
            (const __attribute__((address_space(1))) unsigned*)(src + bl * NH + lane * 4),
            (__attribute__((address_space(3))) unsigned*)&Lhex[bl][lh * 256], 16, 0, 17);
      }
      // x-path MFMA overlaps the DMA round trip
      acc0 = __builtin_amdgcn_mfma_f32_16x16x32_bf16(xfa0, wih_hi[0][0], acc0, 0, 0, 0);
      acc0 = __builtin_amdgcn_mfma_f32_16x16x32_bf16(xfa0, wih_lo[0][0], acc0, 0, 0, 0);
      acc1 = __builtin_amdgcn_mfma_f32_16x16x32_bf16(xfa0, wih_hi[1][0], acc1, 0, 0, 0);
      acc1 = __builtin_amdgcn_mfma_f32_16x16x32_bf16(xfa0, wih_lo[1][0], acc1, 0, 0, 0);
      acc0 = __builtin_amdgcn_mfma_f32_16x16x32_bf16(xfa1, wih_hi[0][1], acc0, 0, 0, 0);
      acc0 = __builtin_amdgcn_mfma_f32_16x16x32_bf16(xfa1, wih_lo[0][1], acc0, 0, 0, 0);
      acc1 = __builtin_amdgcn_mfma_f32_16x16x32_bf16(xfa1, wih_hi[1][1], acc1, 0, 0, 0);
      acc1 = __builtin_amdgcn_mfma_f32_16x16x32_bf16(xfa1, wih_lo[1][1], acc1, 0, 0, 0);
      asm volatile("s_waitcnt vmcnt(0)" ::: "memory");  // DMA landed in LDS
      __builtin_amdgcn_s_barrier();                      // S1
    } else {
      // x-path MFMA while loaders poll/stage
      acc0 = __builtin_amdgcn_mfma_f32_16x16x32_bf16(xfa0, wih_hi[0][0], acc0, 0, 0, 0);
      acc0 = __builtin_amdgcn_mfma_f32_16x16x32_bf16(xfa0, wih_lo[0][0], acc0, 0, 0, 0);
      acc1 = __builtin_amdgcn_mfma_f32_16x16x32_bf16(xfa0, wih_hi[1][0], acc1, 0, 0, 0);
      acc1 = __builtin_amdgcn_mfma_f32_16x16x32_bf16(xfa0, wih_lo[1][0], acc1, 0, 0, 0);
      acc0 = __builtin_amdgcn_mfma_f32_16x16x32_bf16(xfa1, wih_hi[0][1], acc0, 0, 0, 0);
      acc0 = __builtin_amdgcn_mfma_f32_16x16x32_bf16(xfa1, wih_lo[0][1], acc0, 0, 0, 0);
      acc1 = __builtin_amdgcn_mfma_f32_16x16x32_bf16(xfa1, wih_hi[1][1], acc1, 0, 0, 0);
      acc1 = __builtin_amdgcn_mfma_f32_16x16x32_bf16(xfa1, wih_lo[1][1], acc1, 0, 0, 0);
      __builtin_amdgcn_s_barrier();                      // S1 (no pending hazards)
    }

    // h-path: fragments from LDS (row c, u32 cols k0+kc*32+q*8 ..+7)
#pragma unroll
    for (int kc = 0; kc < 2; ++kc) {
      const unsigned* Lr = &Lhex[c][k0 + kc * 32 + q * 8];
      uint4 A = *(const uint4*)(Lr);
      uint4 B = *(const uint4*)(Lr + 4);
      unsigned pw[8] = {A.x, A.y, A.z, A.w, B.x, B.y, B.z, B.w};
      bf16x8 hh, hl;
#pragma unroll
      for (int r = 0; r < 8; ++r) {
        hh[r] = (short)(pw[r] & 0xffffu);
        hl[r] = (short)(pw[r] >> 16);
      }
      acc0 = __builtin_amdgcn_mfma_f32_16x16x32_bf16(hh, whh_hi[0][kc], acc0, 0, 0, 0);
      acc0 = __builtin_amdgcn_mfma_f32_16x16x32_bf16(hl, whh_hi[0][kc], acc0, 0, 0, 0);
      acc0 = __builtin_amdgcn_mfma_f32_16x16x32_bf16(hh, whh_lo[0][kc], acc0, 0, 0, 0);
      acc1 = __builtin_amdgcn_mfma_f32_16x16x32_bf16(hh, whh_hi[1][kc], acc1, 0, 0, 0);
      acc1 = __builtin_amdgcn_mfma_f32_16x16x32_bf16(hl, whh_hi[1][kc], acc1, 0, 0, 0);
      acc1 = __builtin_amdgcn_mfma_f32_16x16x32_bf16(hh, whh_lo[1][kc], acc1, 0, 0, 0);
    }

#pragma unroll
    for (int r = 0; r < 4; ++r) {
      part[0][w][r][lane] = acc0[r];
      part[1][w][r][lane] = acc1[r];
    }
    // S2: lgkm-only drain (part writes visible; vm stores/prefetch fly on)
    asm volatile("s_waitcnt lgkmcnt(0)" ::: "memory");
    __builtin_amdgcn_s_barrier();
    // Lhex WAR: loaders re-stage only after S1(t+1); all ds_reads finished
    // before part-writes (data dependence) which precede S2(t).
    // part WAR: writers rewrite part only after S1(t+1), reached only after
    // reducers pass S2(t) having read part.

    const int tn = (t + 1 < NS) ? t + 1 : t;
    if (w < 2) {  // reducer wave w handles tile u=w
      float g[4];
#pragma unroll
      for (int r = 0; r < 4; ++r) {
        float s = biasr[w];
#pragma unroll
        for (int ww = 0; ww < 8; ++ww) s += part[w][ww][r][lane];
        g[r] = s;
        gl[w][q * 4 + r][c] = g[r];  // D layout: row(batch)=(lane>>4)*4+r, col=lane&15
      }
      // same-wave LDS RAW: compiler inserts lgkmcnt waits
      const int bb = lane & 15;
      float gi = gl[w][bb][j2];
      float gf = gl[w][bb][4 + j2];
      float gg = gl[w][bb][8 + j2];
      float go = gl[w][bb][12 + j2];
      float cn = sigm(gf) * cst + sigm(gi) * tanh_f(gg);
      cst = cn;
      float hv = sigm(go) * tanh_f(cn);

      // publish h (critical path): sc1 store to MALL, ack, then flag
      unsigned short ha = f2bf(hv), la = f2bf(hv - bf2f(ha));
      unsigned int* dst = hex + (size_t)((t + 1) & 1) * (NB * NH) + (size_t)eb * NH;
      __hip_atomic_store(dst + jg, (unsigned)ha | ((unsigned)la << 16),
                         __ATOMIC_RELAXED, __HIP_MEMORY_SCOPE_AGENT);
      asm volatile("s_waitcnt vmcnt(0)" ::: "memory");  // hex store at MALL
      if (lane == 0)
        __hip_atomic_store(flags + n * 2 + w, (unsigned)(t + 2),
                           __ATOMIC_RELAXED, __HIP_MEMORY_SCOPE_AGENT);

      // deferred, non-critical stores (normal cached path)
      out[((size_t)eb * NS + t) * NH + jg] = hv;
      if (t == NS - 1) {
        size_t hoff = (size_t)NB * NS * NH;
        out[hoff + (size_t)eb * NH + jg] = hv;
        out[hoff + (size_t)NB * NH + (size_t)eb * NH + jg] = cn;
      }
      // x prefetch last (in flight during next S1 wait)
      const unsigned short* xrn = xbase + (size_t)tn * NI;
      xfa0 = *(const bf16x8*)(xrn);
      xfa1 = *(const bf16x8*)(xrn + 32);
    } else {
      // writers + loaders: prefetch next x during reducer epilogue
      const unsigned short* xrn = xbase + (size_t)tn * NI;
      xfa0 = *(const bf16x8*)(xrn);
      xfa1 = *(const bf16x8*)(xrn + 32);
    }
  }
}

extern "C" void kernel_launch(void* const* d_in, const int* in_sizes, int n_in,
                              void* d_out, int out_size, void* d_ws, size_t ws_size,
                              hipStream_t stream) {
  if (ws_size < WS_BYTES_NEEDED) return;  // fail visibly (poisoned d_out) rather than corrupt

  const float* x   = (const float*)d_in[0];
  const float* h0  = (const float*)d_in[1];
  const float* c0  = (const float*)d_in[2];
  const float* Wih = (const float*)d_in[3];
  const float* bih = (const float*)d_in[4];
  const float* Whh = (const float*)d_in[5];
  const float* bhh = (const float*)d_in[6];
  float* out = (float*)d_out;
  unsigned int* ws = (unsigned int*)d_ws;
  unsigned short* xbptr = (unsigned short*)(ws + XBF_OFF);

  k_xconv<<<dim3(16384), dim3(256), 0, stream>>>(x, xbptr);
  k_init<<<dim3(128), dim3(256), 0, stream>>>(h0, ws);

  void* args[] = {(void*)&Wih, (void*)&bih, (void*)&Whh, (void*)&bhh,
                  (void*)&c0,  (void*)&out, (void*)&ws};
  hipLaunchCooperativeKernel((const void*)k_lstm, dim3(256), dim3(512), args, 0, stream);
}

// Round 9
// 1727.264 us; speedup vs baseline: 3.2454x; 1.9109x over previous
//
#include <hip/hip_runtime.h>
#include <stdint.h>

#define NB 64
#define NS 512
#define NI 512
#define NH 512

typedef __attribute__((ext_vector_type(8))) short bf16x8;
typedef __attribute__((ext_vector_type(4))) float f32x4;

__device__ __forceinline__ unsigned short f2bf(float f) {
  unsigned u = __float_as_uint(f);
  return (unsigned short)((u + 0x7fffu + ((u >> 16) & 1u)) >> 16);
}
__device__ __forceinline__ float bf2f(unsigned short h) {
  return __uint_as_float(((unsigned)h) << 16);
}
__device__ __forceinline__ float sigm(float x) { return 1.0f / (1.0f + __expf(-x)); }
__device__ __forceinline__ float tanh_f(float x) {
  float e = __expf(-2.0f * fabsf(x));
  return copysignf((1.0f - e) / (1.0f + e), x);
}

// ws layout (u32 units):
//  [0,512):   flags[8 groups][2 waves][32 slices] = steps published (monotonic)
//  [1024,+):  x_bf16 as u16[64][512][512]
#define FLAGS_OFF 0
#define XBF_OFF 1024
#define WS_BYTES_NEEDED ((size_t)XBF_OFF * 4 + (size_t)NB * NS * NI * 2)

__global__ __launch_bounds__(256) void k_xconv(const float* __restrict__ x,
                                               unsigned short* __restrict__ xb) {
  size_t i = ((size_t)blockIdx.x * 256 + threadIdx.x) * 4;
  float4 v = *(const float4*)(x + i);
  ushort4 o;
  o.x = f2bf(v.x); o.y = f2bf(v.y); o.z = f2bf(v.z); o.w = f2bf(v.w);
  *(ushort4*)(xb + i) = o;
}

__global__ __launch_bounds__(256) void k_init(unsigned int* __restrict__ ws) {
  int idx = blockIdx.x * 256 + threadIdx.x;
  if (idx < 512) ws[FLAGS_OFF + idx] = 0u;  // no steps published yet
}

// Persistent cooperative LSTM. grid 256 WGs x 512 thr.
// Group g = bid&7: 8 batches [g*8, g*8+8). Slice s = bid>>3: h-cols [s*16,+16),
// all 4 gates. Wave w = K-eighth (64 K-cols); 4 gate-tile 16x16 MFMA accs
// (A rows 8-15 duplicate batches 0-7; duplicates ignored in the reduction).
//
// h exchange THROUGH `out` (per-step-unique addresses -> no stale-cache hazard,
// no fences, no backpressure):
//   producers (waves 0,1): sc1 u32 store of fp32 hv to out[b][t][j]  (the store
//     we owe anyway) + vmcnt ack + sc1 flag (proven R2-R7 primitives only).
//   consumers (loader waves 6,7): poll 32 flags each (sc1 atomic loads), then
//     stage 4 out-rows each (8KB) via CACHED global_load_lds -> L2-deduped
//     across the 32 same-group WGs. t=0 stages from the h0 input instead.
// Consumers split fp32 h -> bf16 hi/lo in-register (same arithmetic as R1-R7).
__global__ __launch_bounds__(512, 2) void k_lstm(
    const float* __restrict__ Wih, const float* __restrict__ bih,
    const float* __restrict__ Whh, const float* __restrict__ bhh,
    const float* __restrict__ h0, const float* __restrict__ c0,
    float* __restrict__ out, unsigned int* __restrict__ ws) {
  const int tid = threadIdx.x;
  const int lane = tid & 63;
  const int w = tid >> 6;   // K-eighth
  const int q = lane >> 4;
  const int c = lane & 15;
  const int b8 = lane & 7;
  const int k0 = w * 64;
  const int g = blockIdx.x & 7;
  const int s = blockIdx.x >> 3;

  unsigned int* flagsG = ws + FLAGS_OFF + g * 64;  // [2 waves][32 slices]
  const unsigned short* xb = (const unsigned short*)(ws + XBF_OFF);

  // ---- weight fragments (hi/lo bf16 split): 4 gates x 2 K-chunks ----
  // B-frag: col = c -> gate row wrow; k = q*8 + r within chunk.
  bf16x8 wih_hi[4][2], wih_lo[4][2], whh_hi[4][2], whh_lo[4][2];
#pragma unroll
  for (int g4 = 0; g4 < 4; ++g4) {
    const int wrow = g4 * 512 + s * 16 + c;
#pragma unroll
    for (int kc = 0; kc < 2; ++kc) {
      const int kb = k0 + kc * 32 + q * 8;
      const float* pi = Wih + (size_t)wrow * NI + kb;
      const float* ph = Whh + (size_t)wrow * NH + kb;
      float4 i0 = *(const float4*)pi, i1 = *(const float4*)(pi + 4);
      float4 h0v = *(const float4*)ph, h1v = *(const float4*)(ph + 4);
      float vi[8] = {i0.x, i0.y, i0.z, i0.w, i1.x, i1.y, i1.z, i1.w};
      float vh[8] = {h0v.x, h0v.y, h0v.z, h0v.w, h1v.x, h1v.y, h1v.z, h1v.w};
#pragma unroll
      for (int r = 0; r < 8; ++r) {
        unsigned short a = f2bf(vi[r]);
        wih_hi[g4][kc][r] = (short)a;
        wih_lo[g4][kc][r] = (short)f2bf(vi[r] - bf2f(a));
        unsigned short b = f2bf(vh[r]);
        whh_hi[g4][kc][r] = (short)b;
        whh_lo[g4][kc][r] = (short)f2bf(vh[r] - bf2f(b));
      }
    }
  }

  // reducer mapping (waves 0,1): lane -> (batch bg = g*8 + w*4 + q, col jg)
  const int bgc = g * 8 + ((w * 4 + q) & 7);  // clamped for non-reducer waves
  const int jg = s * 16 + c;
  const float bI = bih[jg] + bhh[jg];
  const float bF = bih[512 + jg] + bhh[512 + jg];
  const float bG = bih[1024 + jg] + bhh[1024 + jg];
  const float bO = bih[1536 + jg] + bhh[1536 + jg];
  float cst = c0[(size_t)bgc * NH + jg];

  __shared__ float hexL[8][516];       // staged h_{t-1} (fp32), 8 batches x 512
  __shared__ float part[4][8][4][72];  // [gate][wave][reg][col]

  const unsigned short* xrow = xb + (size_t)(g * 8 + b8) * NS * NI + k0 + q * 8;
  bf16x8 xf0 = *(const bf16x8*)(xrow);
  bf16x8 xf1 = *(const bf16x8*)(xrow + 32);

#pragma unroll 1
  for (int t = 0; t < NS; ++t) {
    // ---- loader waves 6,7: poll + stage h_{t-1} ----
    if (w >= 6) {
      const int lh = w - 6;  // stages batches [lh*4, lh*4+4)
      if (t > 0) {
        const unsigned tgt = (unsigned)t;
        const unsigned* fp = flagsG + lh * 32 + (lane & 31);
        unsigned fl = __hip_atomic_load(fp, __ATOMIC_RELAXED, __HIP_MEMORY_SCOPE_AGENT);
        while (!__all((int)(fl >= tgt)))
          fl = __hip_atomic_load(fp, __ATOMIC_RELAXED, __HIP_MEMORY_SCOPE_AGENT);
        asm volatile("" ::: "memory");  // keep DMA below the poll
      }
#pragma unroll
      for (int r4 = 0; r4 < 4; ++r4) {
        const int bl = lh * 4 + r4;
        const float* srow = (t == 0)
            ? (h0 + (size_t)(g * 8 + bl) * NH)
            : (out + ((size_t)(g * 8 + bl) * NS + (t - 1)) * NH);
        __builtin_amdgcn_global_load_lds(
            (const __attribute__((address_space(1))) unsigned*)(srow + lane * 4),
            (__attribute__((address_space(3))) unsigned*)&hexL[bl][0], 16, 0, 0);
        __builtin_amdgcn_global_load_lds(
            (const __attribute__((address_space(1))) unsigned*)(srow + 256 + lane * 4),
            (__attribute__((address_space(3))) unsigned*)&hexL[bl][256], 16, 0, 0);
      }
    }

    // ---- x-path MFMA (all waves; loaders' overlaps their DMA round trip) ----
    f32x4 acc[4];
#pragma unroll
    for (int g4 = 0; g4 < 4; ++g4) acc[g4] = (f32x4){0.f, 0.f, 0.f, 0.f};
#pragma unroll
    for (int g4 = 0; g4 < 4; ++g4) {
      acc[g4] = __builtin_amdgcn_mfma_f32_16x16x32_bf16(xf0, wih_hi[g4][0], acc[g4], 0, 0, 0);
      acc[g4] = __builtin_amdgcn_mfma_f32_16x16x32_bf16(xf0, wih_lo[g4][0], acc[g4], 0, 0, 0);
      acc[g4] = __builtin_amdgcn_mfma_f32_16x16x32_bf16(xf1, wih_hi[g4][1], acc[g4], 0, 0, 0);
      acc[g4] = __builtin_amdgcn_mfma_f32_16x16x32_bf16(xf1, wih_lo[g4][1], acc[g4], 0, 0, 0);
    }
    if (w >= 6) asm volatile("s_waitcnt vmcnt(0)" ::: "memory");  // DMA landed
    __builtin_amdgcn_s_barrier();  // S1: h staged
    asm volatile("" ::: "memory");

    // ---- h-path: fp32 from LDS -> hi/lo bf16 -> 3-term MFMA ----
#pragma unroll
    for (int kc = 0; kc < 2; ++kc) {
      const float* hp = &hexL[b8][k0 + kc * 32 + q * 8];
      float4 A = *(const float4*)hp;
      float4 B = *(const float4*)(hp + 4);
      float hv8[8] = {A.x, A.y, A.z, A.w, B.x, B.y, B.z, B.w};
      bf16x8 hh, hl;
#pragma unroll
      for (int r = 0; r < 8; ++r) {
        unsigned short a = f2bf(hv8[r]);
        hh[r] = (short)a;
        hl[r] = (short)f2bf(hv8[r] - bf2f(a));
      }
#pragma unroll
      for (int g4 = 0; g4 < 4; ++g4) {
        acc[g4] = __builtin_amdgcn_mfma_f32_16x16x32_bf16(hh, whh_hi[g4][kc], acc[g4], 0, 0, 0);
        acc[g4] = __builtin_amdgcn_mfma_f32_16x16x32_bf16(hl, whh_hi[g4][kc], acc[g4], 0, 0, 0);
        acc[g4] = __builtin_amdgcn_mfma_f32_16x16x32_bf16(hh, whh_lo[g4][kc], acc[g4], 0, 0, 0);
      }
    }

#pragma unroll
    for (int g4 = 0; g4 < 4; ++g4)
#pragma unroll
      for (int r = 0; r < 4; ++r) part[g4][w][r][lane] = acc[g4][r];

    asm volatile("s_waitcnt lgkmcnt(0)" ::: "memory");
    __builtin_amdgcn_s_barrier();  // S2: part visible
    asm volatile("" ::: "memory");
    // WAR safety: hexL/part rewritten only after S1(t+1)/S2(t+1)-side barriers,
    // which require every wave (incl. readers below) to arrive first.

    const int tn = (t + 1 < NS) ? t + 1 : t;
    if (w < 2) {  // reducers: lane owns (b = w*4+q, j = c); writer p=w copy only
      float sI = bI, sF = bF, sG = bG, sO = bO;
      const int cidx = c + w * 16;
#pragma unroll
      for (int ww = 0; ww < 8; ++ww) {
        sI += part[0][ww][q][cidx];
        sF += part[1][ww][q][cidx];
        sG += part[2][ww][q][cidx];
        sO += part[3][ww][q][cidx];
      }
      float cn = sigm(sF) * cst + sigm(sI) * tanh_f(sG);
      cst = cn;
      float hv = sigm(sO) * tanh_f(cn);

      // publish: sc1 store of hv into out (the output store IS the exchange)
      unsigned* dst = (unsigned*)out + ((size_t)bgc * NS + t) * NH + jg;
      __hip_atomic_store(dst, __float_as_uint(hv), __ATOMIC_RELAXED, __HIP_MEMORY_SCOPE_AGENT);
      asm volatile("s_waitcnt vmcnt(0)" ::: "memory");  // at MALL
      if (lane == 0)
        __hip_atomic_store(flagsG + w * 32 + s, (unsigned)(t + 1),
                           __ATOMIC_RELAXED, __HIP_MEMORY_SCOPE_AGENT);

      if (t == NS - 1) {  // final h/c tail (plain; flushed at kernel end)
        size_t hoff = (size_t)NB * NS * NH;
        out[hoff + (size_t)bgc * NH + jg] = hv;
        out[hoff + (size_t)NB * NH + (size_t)bgc * NH + jg] = cn;
      }
    }
    // x prefetch for t+1 (in flight across next S1 wait)
    xf0 = *(const bf16x8*)(xrow + (size_t)tn * NI);
    xf1 = *(const bf16x8*)(xrow + (size_t)tn * NI + 32);
  }
}

extern "C" void kernel_launch(void* const* d_in, const int* in_sizes, int n_in,
                              void* d_out, int out_size, void* d_ws, size_t ws_size,
                              hipStream_t stream) {
  if (ws_size < WS_BYTES_NEEDED) return;  // fail visibly rather than corrupt

  const float* x   = (const float*)d_in[0];
  const float* h0  = (const float*)d_in[1];
  const float* c0  = (const float*)d_in[2];
  const float* Wih = (const float*)d_in[3];
  const float* bih = (const float*)d_in[4];
  const float* Whh = (const float*)d_in[5];
  const float* bhh = (const float*)d_in[6];
  float* out = (float*)d_out;
  unsigned int* ws = (unsigned int*)d_ws;
  unsigned short* xbptr = (unsigned short*)(ws + XBF_OFF);

  k_xconv<<<dim3(16384), dim3(256), 0, stream>>>(x, xbptr);
  k_init<<<dim3(2), dim3(256), 0, stream>>>(ws);

  void* args[] = {(void*)&Wih, (void*)&bih, (void*)&Whh, (void*)&bhh,
                  (void*)&h0,  (void*)&c0,  (void*)&out, (void*)&ws};
  hipLaunchCooperativeKernel((const void*)k_lstm, dim3(256), dim3(512), args, 0, stream);
}